// Round 6
// baseline (68.224 us; speedup 1.0000x reference)
//
#include <hip/hip_runtime.h>
#include <math.h>

#define H 256
#define W 256
#define HW (H * W)
#define CH 24
#define NK 63

typedef short v8s __attribute__((ext_vector_type(8)));
typedef short v4s __attribute__((ext_vector_type(4)));
typedef float v4f __attribute__((ext_vector_type(4)));

// ---------------- RBF helpers: 9-tap window (J=+/-4) -------------------------
__device__ __forceinline__ float rbf_val(float v, const float* ms, const float* ws,
                                         int ch, float m0, float inv_step) {
    int kc = (int)floorf((v - m0) * inv_step + 0.5f);
    kc = min(max(kc, 4), NK - 5);
    float s = 0.f;
    #pragma unroll
    for (int j = 0; j < 9; ++j) {
        int k = kc - 4 + j;
        float d = v - ms[k];
        s = fmaf(__expf(d * d * -0.005f), ws[ch * NK + k], s);
    }
    return s;
}
__device__ __forceinline__ float rbf_der(float v, const float* ms, const float* ws,
                                         int ch, float m0, float inv_step) {
    int kc = (int)floorf((v - m0) * inv_step + 0.5f);
    kc = min(max(kc, 4), NK - 5);
    float s = 0.f;
    #pragma unroll
    for (int j = 0; j < 9; ++j) {
        int k = kc - 4 + j;
        float d = v - ms[k];
        s = fmaf(__expf(d * d * -0.005f) * d * -0.01f, ws[ch * NK + k], s);
    }
    return s;
}

__device__ __forceinline__ short f2bf(float v) {
    unsigned u = __float_as_uint(v);
    u += 0x7fff + ((u >> 16) & 1);
    return (short)(u >> 16);
}

// ---------------- prep: norms, f0n/f0t, MFMA A-fragment pack ------------------
// Abuf: [mode 2][mtile 2][kstep 19][lane 64] v8s. k = tap*24 + c, K 600->608.
__global__ void k_prep(const float* __restrict__ f0, const float* __restrict__ f1,
                       float* __restrict__ f0n, float* __restrict__ f0t,
                       v8s* __restrict__ abuf) {
    __shared__ float red[256];
    int tid = threadIdx.x;
    float s1 = 0.f;
    for (int i = tid; i < 14400; i += 256) s1 += f1[i] * f1[i];
    red[tid] = s1; __syncthreads();
    for (int off = 128; off; off >>= 1) { if (tid < off) red[tid] += red[tid + off]; __syncthreads(); }
    float inv1 = 1.f / sqrtf(red[0]);
    __syncthreads();
    if (blockIdx.x == 0) {
        float s0 = 0.f;
        for (int i = tid; i < 600; i += 256) s0 += f0[i] * f0[i];
        red[tid] = s0; __syncthreads();
        for (int off = 128; off; off >>= 1) { if (tid < off) red[tid] += red[tid + off]; __syncthreads(); }
        float inv0 = 1.f / sqrtf(red[0]);
        for (int i = tid; i < 600; i += 256) {
            int c = i / 25, k = i % 25;
            f0n[i] = f0[i] * inv0;
            f0t[i] = f0[c * 25 + (24 - k)] * inv0;
        }
    }
    int gid = blockIdx.x * 256 + tid;
    int lane = gid & 63;
    int rest = gid >> 6;
    int s = rest % 19;
    int md = rest / 19;
    int mode = md >> 1, m = md & 1;
    int o = m * 16 + (lane & 15);
    v8s av;
    #pragma unroll
    for (int j = 0; j < 8; ++j) {
        int k = 32 * s + 8 * (lane >> 4) + j;
        float wv = 0.f;
        if (o < CH && k < 600) {
            int t = k / 24, c = k % 24;
            wv = (mode == 0) ? f1[(o * CH + c) * 25 + t]
                             : f1[(c * CH + o) * 25 + (24 - t)];
            wv *= inv1;
        }
        av[j] = f2bf(wv);
    }
    abuf[gid] = av;
}

// ---------------- fused A: conv1+rbf0 -> conv2 MFMA + rbf1 -------------------
// 8x8 output tile, 4 waves, grid 32x32 = 1024 blocks (4 blocks/CU).
// xs: 16x16 x-window (clamped). t1: 12x12 haloed region, ch-minor bf16.
// tb output layout: [HW][24] bf16 (channel-minor).
__global__ __launch_bounds__(256, 4) void k_fuseA(const float* __restrict__ x,
        const float* __restrict__ f0n, const v8s* __restrict__ abuf,
        const float* __restrict__ mean, const float* __restrict__ aw0,
        const float* __restrict__ aw1, short* __restrict__ tb) {
    __shared__ float xs[16 * 16];
    __shared__ __align__(16) short t1[144 * 24];   // 6912 B
    __shared__ float ms[NK];
    __shared__ float ws0[CH * NK];
    __shared__ float ws1[CH * NK];
    int tid = threadIdx.x;
    int x0 = blockIdx.x * 8, y0 = blockIdx.y * 8;
    {   // stage x window: row r <-> clamp(y0+r-4), col c <-> clamp(x0+c-4)
        int r = tid >> 4, cL = tid & 15;
        int gy = min(max(y0 + r - 4, 0), H - 1);
        int gx = min(max(x0 + cL - 4, 0), W - 1);
        xs[tid] = x[gy * W + gx];
    }
    for (int i = tid; i < NK; i += 256) ms[i] = mean[i];
    for (int i = tid; i < CH * NK; i += 256) { ws0[i] = aw0[i]; ws1[i] = aw1[i]; }
    __syncthreads();
    float m0 = ms[0];
    float inv_step = (float)(NK - 1) / (ms[NK - 1] - m0);

    // stage 1: t1(yi,xi) = rbf0(conv1 @ clamped pos (sy,sx)), double-clamp = rep pad
    if (tid < 144) {
        int yi = (tid * 5462) >> 16;        // tid / 12
        int xi = tid - yi * 12;
        int sy = min(max(y0 + yi - 2, 0), H - 1);
        int sx = min(max(x0 + xi - 2, 0), W - 1);
        int iy[5], ix[5];
        #pragma unroll
        for (int u = 0; u < 5; ++u) {
            iy[u] = min(max(sy + u - 2, 0), H - 1) - (y0 - 4);
            ix[u] = min(max(sx + u - 2, 0), W - 1) - (x0 - 4);
        }
        float in_[25];
        #pragma unroll
        for (int u = 0; u < 5; ++u)
            #pragma unroll
            for (int v = 0; v < 5; ++v) in_[u * 5 + v] = xs[iy[u] * 16 + ix[v]];
        #pragma unroll 1
        for (int og = 0; og < 3; ++og) {
            v8s pk;
            #pragma unroll
            for (int oj = 0; oj < 8; ++oj) {
                int o = og * 8 + oj;
                float a = 0.f;
                #pragma unroll
                for (int k = 0; k < 25; ++k) a = fmaf(in_[k], f0n[o * 25 + k], a);
                pk[oj] = f2bf(rbf_val(a, ms, ws0, o, m0, inv_step));
            }
            *(v8s*)&t1[tid * 24 + og * 8] = pk;
        }
    }
    __syncthreads();

    // stage 2: conv2 MFMA; wave = one 16-px N-tile (2 rows of 8)
    int lane = tid & 63, wv_ = tid >> 6;
    int p = lane & 15, q = lane >> 4;
    int row = (wv_ * 16 + p) >> 3, col = p & 7;
    v4f a0v = {0.f,0.f,0.f,0.f}, a1v = {0.f,0.f,0.f,0.f};
    #pragma unroll 1
    for (int s = 0; s < 19; ++s) {
        int k0 = 32 * s + 8 * q;
        int t  = (k0 * 2731) >> 16;          // k0 / 24
        int c0 = k0 - t * 24;
        int u  = (t * 3277) >> 14;           // t / 5
        int v  = t - 5 * u;
        v8s b  = *(const v8s*)&t1[((row + u) * 12 + (col + v)) * 24 + c0];
        v8s af0 = abuf[s * 64 + lane];
        v8s af1 = abuf[1216 + s * 64 + lane];
        a0v = __builtin_amdgcn_mfma_f32_16x16x32_bf16(af0, b, a0v, 0, 0, 0);
        a1v = __builtin_amdgcn_mfma_f32_16x16x32_bf16(af1, b, a1v, 0, 0, 0);
    }
    // epilogue: rbf1 -> tb[pix][ch], contiguous 8B stores
    int pix = (y0 + row) * W + (x0 + col);
    v4s st;
    #pragma unroll
    for (int j = 0; j < 4; ++j)
        st[j] = f2bf(rbf_val(a0v[j], ms, ws1, q * 4 + j, m0, inv_step));
    *(v4s*)&tb[pix * 24 + q * 4] = st;
    if (q < 2) {
        #pragma unroll
        for (int j = 0; j < 4; ++j)
            st[j] = f2bf(rbf_val(a1v[j], ms, ws1, 16 + q * 4 + j, m0, inv_step));
        *(v4s*)&tb[pix * 24 + 16 + q * 4] = st;
    }
}

// ---------------- fused B: convT2 MFMA + rbf' -> convT1 + final --------------
// 8x8 output tile, grid 32x32. tbt: 16x16 tb window (zero pad), ch-minor.
// t3: 12x12 haloed region, stride 25 floats. 9 N-tiles = 144 px exactly.
__global__ __launch_bounds__(256, 4) void k_fuseB(const short* __restrict__ tb,
        const v8s* __restrict__ abuf, const float* __restrict__ f0t,
        const float* __restrict__ mean, const float* __restrict__ aw0,
        const float* __restrict__ x, const float* __restrict__ y,
        const float* __restrict__ lamp, float* __restrict__ out) {
    __shared__ __align__(16) short tbt[256 * 24];  // 12288 B
    __shared__ float t3[144 * 25];                 // 14400 B
    __shared__ float ms[NK];
    __shared__ float ws[CH * NK];
    __shared__ float red[256];
    int tid = threadIdx.x;
    int x0 = blockIdx.x * 8, y0 = blockIdx.y * 8;
    {   // stage tb window: pixel tid of 16x16 <-> image (y0+r-4, x0+c-4), zero pad
        int r = tid >> 4, cL = tid & 15;
        int gy = y0 + r - 4, gx = x0 + cL - 4;
        if (gy >= 0 && gy < H && gx >= 0 && gx < W) {
            const v8s* src = (const v8s*)&tb[(gy * W + gx) * 24];
            *(v8s*)&tbt[tid * 24]      = src[0];
            *(v8s*)&tbt[tid * 24 + 8]  = src[1];
            *(v8s*)&tbt[tid * 24 + 16] = src[2];
        } else {
            v8s z = {0,0,0,0,0,0,0,0};
            *(v8s*)&tbt[tid * 24]      = z;
            *(v8s*)&tbt[tid * 24 + 8]  = z;
            *(v8s*)&tbt[tid * 24 + 16] = z;
        }
    }
    for (int i = tid; i < NK; i += 256) ms[i] = mean[i];
    for (int i = tid; i < CH * NK; i += 256) ws[i] = aw0[i];
    __syncthreads();
    float m0 = ms[0];
    float inv_step = (float)(NK - 1) / (ms[NK - 1] - m0);

    // convT2 MFMA (mode-1 A-frags): 9 tiles; wave w handles tiles w, w+4, w+8
    int lane = tid & 63, wv_ = tid >> 6;
    int p = lane & 15, q = lane >> 4;
    const v8s* ap = abuf + 2432;
    #pragma unroll 1
    for (int g3 = 0; g3 < 3; ++g3) {
        int tIdx = wv_ + 4 * g3;
        if (tIdx > 8) break;
        int f = tIdx * 16 + p;               // flat t3 px, < 144
        int row = (f * 5462) >> 16;          // f / 12
        int col = f - row * 12;
        v4f a0v = {0.f,0.f,0.f,0.f}, a1v = {0.f,0.f,0.f,0.f};
        #pragma unroll 1
        for (int s = 0; s < 19; ++s) {
            int k0 = 32 * s + 8 * q;
            int t  = (k0 * 2731) >> 16;
            int c0 = k0 - t * 24;
            int u  = (t * 3277) >> 14;
            int v  = t - 5 * u;
            v8s b  = *(const v8s*)&tbt[((row + u) * 16 + (col + v)) * 24 + c0];
            v8s af0 = ap[s * 64 + lane];
            v8s af1 = ap[1216 + s * 64 + lane];
            a0v = __builtin_amdgcn_mfma_f32_16x16x32_bf16(af0, b, a0v, 0, 0, 0);
            a1v = __builtin_amdgcn_mfma_f32_16x16x32_bf16(af1, b, a1v, 0, 0, 0);
        }
        int gy = y0 + row - 2, gx = x0 + col - 2;
        bool inimg = (gy >= 0 && gy < H && gx >= 0 && gx < W);
        #pragma unroll
        for (int j = 0; j < 4; ++j)
            t3[f * 25 + q * 4 + j] = inimg ? rbf_der(a0v[j], ms, ws, q * 4 + j, m0, inv_step) : 0.f;
        if (q < 2) {
            #pragma unroll
            for (int j = 0; j < 4; ++j)
                t3[f * 25 + 16 + q * 4 + j] = inimg ? rbf_der(a1v[j], ms, ws, 16 + q * 4 + j, m0, inv_step) : 0.f;
        }
    }
    __syncthreads();

    // convT1 (24->1, pre-flipped f0t) + final; 4-way channel split across waves
    int g = __builtin_amdgcn_readfirstlane(tid >> 6);
    int px = tid & 63, pr = px >> 3, pc = px & 7;
    float a = 0.f;
    #pragma unroll 1
    for (int cc = 0; cc < 6; ++cc) {
        int c = g * 6 + cc;
        const float* fb = f0t + c * 25;
        #pragma unroll
        for (int u = 0; u < 5; ++u)
            #pragma unroll
            for (int v = 0; v < 5; ++v)
                a = fmaf(t3[((pr + u) * 12 + (pc + v)) * 25 + c], fb[u * 5 + v], a);
    }
    red[tid] = a;
    __syncthreads();
    if (tid < 64) {
        float tot = red[tid] + red[64 + tid] + red[128 + tid] + red[192 + tid];
        int pix = (y0 + pr) * W + (x0 + pc);
        float elam = __expf(lamp[0]);
        float xv = x[pix], yv = y[pix];
        out[pix] = xv - (tot + elam * (xv - yv));
    }
}

extern "C" void kernel_launch(void* const* d_in, const int* in_sizes, int n_in,
                              void* d_out, int out_size, void* d_ws, size_t ws_size,
                              hipStream_t stream) {
    const float* x    = (const float*)d_in[0];
    const float* y    = (const float*)d_in[1];
    const float* f0   = (const float*)d_in[3];
    const float* f1   = (const float*)d_in[4];
    const float* aw0  = (const float*)d_in[5];
    const float* aw1  = (const float*)d_in[6];
    const float* mean = (const float*)d_in[7];
    const float* lamp = (const float*)d_in[8];
    float* out = (float*)d_out;

    float* w   = (float*)d_ws;
    float* f0n = w;                  // 600
    float* f0t = w + 640;            // 600
    v8s*  abuf = (v8s*)(w + 1536);   // 4864 * 16 B
    short* tb  = (short*)(w + 32768);

    k_prep<<<19, 256, 0, stream>>>(f0, f1, f0n, f0t, abuf);
    dim3 grid(W / 8, H / 8);         // 32 x 32 = 1024 blocks
    k_fuseA<<<grid, 256, 0, stream>>>(x, f0n, abuf, mean, aw0, aw1, tb);
    k_fuseB<<<grid, 256, 0, stream>>>(tb, abuf, f0t, mean, aw0, x, y, lamp, out);
}